// Round 4
// baseline (512.677 us; speedup 1.0000x reference)
//
#include <hip/hip_runtime.h>
#include <hip/hip_fp16.h>
#include <math.h>

#define NIMG 8
#define PNUM 4000
#define CNUM 91
#define DETK 100
#define TOTALQ (NIMG * PNUM)
#define NEGV  -1000000000.0
#define NEGH  -500000000.0
#define CLAMP64 4.1351665567423558   // float64 nearest to log(1000/16)

// ---- workspace layout (bytes) ----
#define WS_ACT   0                          // f64 [32000]
#define WS_BH    (WS_ACT + TOTALQ * 8)      // f32 [4][32000] planar (clipped box hi)
#define WS_BL    (WS_BH  + TOTALQ * 16)     // f16 [4][32000] planar (box lo residual)
#define WS_LAB   (WS_BL  + TOTALQ * 8)      // u16 [32000]
#define WS_NEED  (WS_LAB + TOTALQ * 2)      // = 1,088,000 B

// =====================================================================
// Kernel A: one wave64 per proposal. Lane-parallel f64 softmax (classes
// 0..63 on lanes, 64..90 on lanes 0..26), fg argmax on raw logits
// (equivalent to prob argmax; ties -> lower class), f64 decode on lane 0.
// =====================================================================
extern "C" __global__ __launch_bounds__(256)
void k_prep(const float* __restrict__ logits,   // [8][4000][91]
            const float* __restrict__ deltas,   // [8][4000][364]
            const float* __restrict__ props,    // [8][4000][4]
            double* __restrict__ w_act,
            float* __restrict__ w_bh,
            __half* __restrict__ w_bl,
            unsigned short* __restrict__ w_lab)
{
    const int wid  = blockIdx.x * 4 + (threadIdx.x >> 6);
    const int lane = threadIdx.x & 63;
    if (wid >= TOTALQ) return;

    const float* lg = logits + (long)wid * CNUM;
    const bool has1 = lane < (CNUM - 64);       // lanes 0..26 also own class 64+lane
    const float l0 = lg[lane];
    const float l1 = has1 ? lg[64 + lane] : 0.0f;

    float m = has1 ? fmaxf(l0, l1) : l0;
    #pragma unroll
    for (int s = 32; s; s >>= 1) m = fmaxf(m, __shfl_xor(m, s));

    const double e0 = exp((double)l0 - (double)m);          // exact f32->f64 sub
    const double e1 = has1 ? exp((double)l1 - (double)m) : 0.0;
    double sum = e0 + e1;
    #pragma unroll
    for (int s = 32; s; s >>= 1) sum += __shfl_xor(sum, s);

    // fg argmax over raw logits c in [1,90], (value desc, class asc)
    float bv; int bc;
    if (lane >= 1) { bv = l0; bc = lane; } else { bv = -INFINITY; bc = 0x7fffffff; }
    if (has1 && l1 > bv) { bv = l1; bc = 64 + lane; }
    #pragma unroll
    for (int s = 32; s; s >>= 1) {
        const float ov = __shfl_xor(bv, s);
        const int   oc = __shfl_xor(bc, s);
        if (ov > bv || (ov == bv && oc < bc)) { bv = ov; bc = oc; }
    }

    if (lane == 0) {
        const int label = bc;
        const double score = exp((double)bv - (double)m) / sum;

        const float* pr = props + (long)wid * 4;
        const double x1p = (double)pr[0], y1p = (double)pr[1];
        const double x2p = (double)pr[2], y2p = (double)pr[3];
        const double w  = x2p - x1p, h = y2p - y1p;
        const double cx = x1p + 0.5 * w, cy = y1p + 0.5 * h;

        const float* dl = deltas + (long)wid * (CNUM * 4) + label * 4;
        const double dx = (double)dl[0] / 10.0;
        const double dy = (double)dl[1] / 10.0;
        const double dw = fmin((double)dl[2] / 5.0, CLAMP64);
        const double dh = fmin((double)dl[3] / 5.0, CLAMP64);

        const double pcx = dx * w + cx;
        const double pcy = dy * h + cy;
        const double pw  = exp(dw) * w;
        const double ph  = exp(dh) * h;

        double x1 = pcx - 0.5 * pw, y1 = pcy - 0.5 * ph;
        double x2 = pcx + 0.5 * pw, y2 = pcy + 0.5 * ph;
        x1 = fmin(fmax(x1, 0.0), 800.0);
        y1 = fmin(fmax(y1, 0.0), 800.0);
        x2 = fmin(fmax(x2, 0.0), 800.0);
        y2 = fmin(fmax(y2, 0.0), 800.0);

        const bool valid = ((x2 - x1) >= 0.01) && ((y2 - y1) >= 0.01) && (score > 0.05);

        w_act[wid] = valid ? score : NEGV;
        w_lab[wid] = (unsigned short)label;

        const float h0 = (float)x1, h1 = (float)y1, h2 = (float)x2, h3 = (float)y2;
        w_bh[0 * TOTALQ + wid] = h0;
        w_bh[1 * TOTALQ + wid] = h1;
        w_bh[2 * TOTALQ + wid] = h2;
        w_bh[3 * TOTALQ + wid] = h3;
        w_bl[0 * TOTALQ + wid] = __float2half((float)(x1 - (double)h0));
        w_bl[1 * TOTALQ + wid] = __float2half((float)(y1 - (double)h1));
        w_bl[2 * TOTALQ + wid] = __float2half((float)(x2 - (double)h2));
        w_bl[3 * TOTALQ + wid] = __float2half((float)(y2 - (double)h3));
    }
}

// =====================================================================
// Kernel B: one block per image. Per-label greedy NMS (cross-label
// suppression in the reference is provably zero thanks to the maxc+1
// label offset), 16 independent waves with NO barriers, then one
// bitonic sort by (score desc, idx asc) = the reference's pick order.
// =====================================================================
extern "C" __global__ __launch_bounds__(1024)
void k_nms(const double* __restrict__ w_act,
           const float* __restrict__ w_bh,
           const __half* __restrict__ w_bl,
           const unsigned short* __restrict__ w_lab,
           float* __restrict__ out)     // [800 lab | 800 sc | 3200 box] f32
{
    __shared__ double act[4096];
    __shared__ unsigned short slab[4096];
    __shared__ float  bh0[PNUM], bh1[PNUM], bh2[PNUM], bh3[PNUM];
    __shared__ __half bl0[PNUM], bl1[PNUM], bl2[PNUM], bl3[PNUM];
    __shared__ unsigned short lists[PNUM];
    __shared__ unsigned short srt[4096];
    __shared__ int cnt[CNUM], off[CNUM], cur[CNUM];

    const int n   = blockIdx.x;
    const int tid = threadIdx.x;
    const long base = (long)n * PNUM;

    for (int j = tid; j < 4096; j += 1024) {
        if (j < PNUM) {
            act[j]  = w_act[base + j];
            slab[j] = w_lab[base + j];
            bh0[j] = w_bh[0 * TOTALQ + base + j];
            bh1[j] = w_bh[1 * TOTALQ + base + j];
            bh2[j] = w_bh[2 * TOTALQ + base + j];
            bh3[j] = w_bh[3 * TOTALQ + base + j];
            bl0[j] = w_bl[0 * TOTALQ + base + j];
            bl1[j] = w_bl[1 * TOTALQ + base + j];
            bl2[j] = w_bl[2 * TOTALQ + base + j];
            bl3[j] = w_bl[3 * TOTALQ + base + j];
        } else { act[j] = NEGV; slab[j] = 0; }
    }
    if (tid < CNUM) { cnt[tid] = 0; cur[tid] = 0; }
    __syncthreads();

    // histogram of VALID candidates by label (1..90)
    for (int j = tid; j < PNUM; j += 1024)
        if (act[j] > 0.0) atomicAdd(&cnt[slab[j]], 1);
    __syncthreads();
    if (tid == 0) { int s = 0; for (int l = 1; l < CNUM; ++l) { off[l] = s; s += cnt[l]; } }
    __syncthreads();
    for (int j = tid; j < PNUM; j += 1024)
        if (act[j] > 0.0) {
            const int l = slab[j];
            const int p = atomicAdd(&cur[l], 1);
            lists[off[l] + p] = (unsigned short)j;   // order within label arbitrary
        }
    __syncthreads();

    // ---- per-label greedy NMS, one wave per label, no barriers ----
    const int wave = tid >> 6, lane = tid & 63;
    for (int l = 1 + wave; l < CNUM; l += 16) {
        const int nn = cnt[l];
        if (nn == 0) continue;
        const int sbase = off[l];
        const int R = (nn + 63) >> 6;
        unsigned long long mask = 0;
        for (int r = 0; r < R; ++r) {
            const int e = (r << 6) + lane;
            if (e < nn) mask |= (1ull << r);
        }
        for (;;) {
            // wave argmax over active: (score desc, original idx asc)
            double bs = -1.0; int bj = 0x7fffffff;
            for (int r = 0; r < R; ++r) if (mask & (1ull << r)) {
                const int j = lists[sbase + (r << 6) + lane];
                const double s = act[j];
                if (s > bs || (s == bs && j < bj)) { bs = s; bj = j; }
            }
            for (int sft = 32; sft; sft >>= 1) {
                const double os = __shfl_xor(bs, sft);
                const int    oj = __shfl_xor(bj, sft);
                if (os > bs || (os == bs && oj < bj)) { bs = os; bj = oj; }
            }
            if (bs < 0.0) break;                     // exhausted (valid scores > 0.05)

            // pick = bj stays kept (act[bj] keeps its score)
            const double px1 = (double)bh0[bj] + (double)__half2float(bl0[bj]);
            const double py1 = (double)bh1[bj] + (double)__half2float(bl1[bj]);
            const double px2 = (double)bh2[bj] + (double)__half2float(bl2[bj]);
            const double py2 = (double)bh3[bj] + (double)__half2float(bl3[bj]);
            const double a1  = (px2 - px1) * (py2 - py1);

            for (int r = 0; r < R; ++r) if (mask & (1ull << r)) {
                const int j = lists[sbase + (r << 6) + lane];
                if (j == bj) { mask &= ~(1ull << r); continue; }
                const double qx1 = (double)bh0[j] + (double)__half2float(bl0[j]);
                const double qy1 = (double)bh1[j] + (double)__half2float(bl1[j]);
                const double qx2 = (double)bh2[j] + (double)__half2float(bl2[j]);
                const double qy2 = (double)bh3[j] + (double)__half2float(bl3[j]);
                const double ix = fmin(px2, qx2) - fmax(px1, qx1);
                const double iy = fmin(py2, qy2) - fmax(py1, qy1);
                const double inter = fmax(ix, 0.0) * fmax(iy, 0.0);
                const double a2  = (qx2 - qx1) * (qy2 - qy1);
                const double uni = fmax(a1 + a2 - inter, 1e-9);
                if (inter / uni > 0.5) { mask &= ~(1ull << r); act[j] = NEGV; }
            }
        }
    }
    __syncthreads();

    // ---- bitonic sort of index handles by (act desc, idx asc) ----
    for (int i = tid; i < 4096; i += 1024) srt[i] = (unsigned short)i;
    __syncthreads();
    for (int k = 2; k <= 4096; k <<= 1) {
        for (int j2 = k >> 1; j2 > 0; j2 >>= 1) {
            #pragma unroll
            for (int t = 0; t < 4; ++t) {
                const int i = tid + (t << 10);
                const int p = i ^ j2;
                if (p > i) {
                    const int a = srt[i], b = srt[p];
                    const double sa = act[a], sb = act[b];
                    const bool aFirst = (sa > sb) || (sa == sb && a < b);
                    const bool up = ((i & k) == 0);
                    if (up ? !aFirst : aFirst) {
                        srt[i] = (unsigned short)b;
                        srt[p] = (unsigned short)a;
                    }
                }
            }
            __syncthreads();
        }
    }

    // ---- emit top-100 ----
    if (tid < DETK) {
        const int r  = srt[tid];
        const bool kp = (act[r] > 0.0);      // kept boxes keep score > 0.05
        const int o  = n * DETK + tid;
        float lab = 0.f, sc = 0.f, b0 = 0.f, b1 = 0.f, b2 = 0.f, b3 = 0.f;
        if (kp) {
            lab = (float)slab[r];
            sc  = (float)act[r];
            b0 = bh0[r]; b1 = bh1[r]; b2 = bh2[r]; b3 = bh3[r];
        }
        out[o]               = lab;
        out[NIMG * DETK + o] = sc;
        out[2 * NIMG * DETK + o * 4 + 0] = b0;
        out[2 * NIMG * DETK + o * 4 + 1] = b1;
        out[2 * NIMG * DETK + o * 4 + 2] = b2;
        out[2 * NIMG * DETK + o * 4 + 3] = b3;
    }
}

// =====================================================================
// Fallback (proven round-3 kernel) in case ws_size < WS_NEED.
// =====================================================================
extern "C" __global__ __launch_bounds__(1024)
void k_fused(const float* __restrict__ logits,
             const float* __restrict__ deltas,
             const float* __restrict__ props,
             float* __restrict__ out)
{
    __shared__ float   bh0[PNUM], bh1[PNUM], bh2[PNUM], bh3[PNUM];
    __shared__ __half  bl0[PNUM], bl1[PNUM], bl2[PNUM], bl3[PNUM];
    __shared__ double  act[PNUM];
    __shared__ unsigned short slab[PNUM];
    __shared__ double  redV[16];
    __shared__ int     redI[16];
    __shared__ double  pbox[4];
    __shared__ int     pidx, pkeep, plab;
    __shared__ int     kidx[DETK], kkeep[DETK];
    __shared__ double  kscore[DETK];
    __shared__ double  kbox[DETK][4];

    const int n   = blockIdx.x;
    const int tid = threadIdx.x;

    for (int j = tid; j < PNUM; j += 1024) {
        const long q = (long)n * PNUM + j;
        const float* lg = logits + q * CNUM;
        float ml = lg[0];
        float bv = lg[1];
        int   lab = 1;
        for (int c = 1; c < CNUM; ++c) {
            const float v = lg[c];
            ml = fmaxf(ml, v);
            if (c >= 2 && v > bv) { bv = v; lab = c; }
        }
        const double m = (double)ml;
        double sum = 0.0;
        for (int c = 0; c < CNUM; ++c) sum += exp((double)lg[c] - m);
        const double score = exp((double)bv - m) / sum;

        const float* pr = props + q * 4;
        const double x1p = (double)pr[0], y1p = (double)pr[1];
        const double x2p = (double)pr[2], y2p = (double)pr[3];
        const double w  = x2p - x1p, h = y2p - y1p;
        const double cx = x1p + 0.5 * w, cy = y1p + 0.5 * h;
        const float* dl = deltas + q * (CNUM * 4) + lab * 4;
        const double dx = (double)dl[0] / 10.0;
        const double dy = (double)dl[1] / 10.0;
        const double dw = fmin((double)dl[2] / 5.0, CLAMP64);
        const double dh = fmin((double)dl[3] / 5.0, CLAMP64);
        const double pcx = dx * w + cx;
        const double pcy = dy * h + cy;
        const double pw  = exp(dw) * w;
        const double ph  = exp(dh) * h;
        double x1 = pcx - 0.5 * pw, y1 = pcy - 0.5 * ph;
        double x2 = pcx + 0.5 * pw, y2 = pcy + 0.5 * ph;
        x1 = fmin(fmax(x1, 0.0), 800.0);
        y1 = fmin(fmax(y1, 0.0), 800.0);
        x2 = fmin(fmax(x2, 0.0), 800.0);
        y2 = fmin(fmax(y2, 0.0), 800.0);
        const bool valid = ((x2 - x1) >= 0.01) && ((y2 - y1) >= 0.01) && (score > 0.05);
        act[j]  = valid ? score : NEGV;
        slab[j] = (unsigned short)lab;
        const float h0 = (float)x1, h1 = (float)y1, h2 = (float)x2, h3 = (float)y2;
        bh0[j] = h0; bh1[j] = h1; bh2[j] = h2; bh3[j] = h3;
        bl0[j] = __float2half((float)(x1 - (double)h0));
        bl1[j] = __float2half((float)(y1 - (double)h1));
        bl2[j] = __float2half((float)(x2 - (double)h2));
        bl3[j] = __float2half((float)(y2 - (double)h3));
    }
    __syncthreads();

    for (int k = 0; k < DETK; ++k) {
        double bv = -INFINITY;
        int    bi = 0x7fffffff;
        #pragma unroll
        for (int t = 0; t < 4; ++t) {
            const int j = tid + t * 1024;
            if (j < PNUM) {
                const double v = act[j];
                if (v > bv) { bv = v; bi = j; }
            }
        }
        #pragma unroll
        for (int s = 32; s; s >>= 1) {
            const double ov = __shfl_xor(bv, s);
            const int    oi = __shfl_xor(bi, s);
            if (ov > bv || (ov == bv && oi < bi)) { bv = ov; bi = oi; }
        }
        if ((tid & 63) == 0) { redV[tid >> 6] = bv; redI[tid >> 6] = bi; }
        __syncthreads();
        if (tid < 64) {
            bv = (tid < 16) ? redV[tid] : -INFINITY;
            bi = (tid < 16) ? redI[tid] : 0x7fffffff;
            #pragma unroll
            for (int s = 8; s; s >>= 1) {
                const double ov = __shfl_xor(bv, s);
                const int    oi = __shfl_xor(bi, s);
                if (ov > bv || (ov == bv && oi < bi)) { bv = ov; bi = oi; }
            }
            if (tid == 0) {
                const int kp = (bv > NEGH) ? 1 : 0;
                pidx = bi; pkeep = kp; plab = (int)slab[bi];
                kidx[k] = bi; kkeep[k] = kp; kscore[k] = bv;
                const double b0 = (double)bh0[bi] + (double)__half2float(bl0[bi]);
                const double b1 = (double)bh1[bi] + (double)__half2float(bl1[bi]);
                const double b2 = (double)bh2[bi] + (double)__half2float(bl2[bi]);
                const double b3 = (double)bh3[bi] + (double)__half2float(bl3[bi]);
                pbox[0] = b0; pbox[1] = b1; pbox[2] = b2; pbox[3] = b3;
                kbox[k][0] = b0; kbox[k][1] = b1; kbox[k][2] = b2; kbox[k][3] = b3;
            }
        }
        __syncthreads();

        const int    pick = pidx;
        const int    kp   = pkeep;
        const int    pl   = plab;
        const double px1 = pbox[0], py1 = pbox[1], px2 = pbox[2], py2 = pbox[3];
        const double a1  = (px2 - px1) * (py2 - py1);
        #pragma unroll
        for (int t = 0; t < 4; ++t) {
            const int j = tid + t * 1024;
            if (j >= PNUM) break;
            if (j == pick) { act[j] = NEGV; continue; }
            if (!kp) continue;
            if ((int)slab[j] != pl) continue;
            if (act[j] <= NEGH) continue;
            const double qx1 = (double)bh0[j] + (double)__half2float(bl0[j]);
            const double qy1 = (double)bh1[j] + (double)__half2float(bl1[j]);
            const double qx2 = (double)bh2[j] + (double)__half2float(bl2[j]);
            const double qy2 = (double)bh3[j] + (double)__half2float(bl3[j]);
            const double ix = fmin(px2, qx2) - fmax(px1, qx1);
            const double iy = fmin(py2, qy2) - fmax(py1, qy1);
            const double inter = fmax(ix, 0.0) * fmax(iy, 0.0);
            const double a2  = (qx2 - qx1) * (qy2 - qy1);
            const double uni = fmax(a1 + a2 - inter, 1e-9);
            if (inter / uni > 0.5) act[j] = NEGV;
        }
        __syncthreads();
    }

    if (tid < DETK) {
        const int kp = kkeep[tid];
        const int o  = n * DETK + tid;
        out[o]               = kp ? (float)slab[kidx[tid]] : 0.0f;
        out[NIMG * DETK + o] = kp ? (float)kscore[tid] : 0.0f;
        #pragma unroll
        for (int i = 0; i < 4; ++i)
            out[2 * NIMG * DETK + o * 4 + i] = kp ? (float)kbox[tid][i] : 0.0f;
    }
}

extern "C" void kernel_launch(void* const* d_in, const int* in_sizes, int n_in,
                              void* d_out, int out_size, void* d_ws, size_t ws_size,
                              hipStream_t stream)
{
    const float* logits = (const float*)d_in[1];
    const float* deltas = (const float*)d_in[2];
    const float* props  = (const float*)d_in[3];
    float* out = (float*)d_out;

    if (ws_size >= (size_t)WS_NEED) {
        char* ws = (char*)d_ws;
        double*         w_act = (double*)(ws + WS_ACT);
        float*          w_bh  = (float*)(ws + WS_BH);
        __half*         w_bl  = (__half*)(ws + WS_BL);
        unsigned short* w_lab = (unsigned short*)(ws + WS_LAB);

        hipLaunchKernelGGL(k_prep, dim3(TOTALQ / 4), dim3(256), 0, stream,
                           logits, deltas, props, w_act, w_bh, w_bl, w_lab);
        hipLaunchKernelGGL(k_nms, dim3(NIMG), dim3(1024), 0, stream,
                           w_act, w_bh, w_bl, w_lab, out);
    } else {
        hipLaunchKernelGGL(k_fused, dim3(NIMG), dim3(1024), 0, stream,
                           logits, deltas, props, out);
    }
}

// Round 5
// 248.867 us; speedup vs baseline: 2.0600x; 2.0600x over previous
//
#include <hip/hip_runtime.h>
#include <hip/hip_fp16.h>
#include <math.h>

#define NIMG 8
#define PNUM 4000
#define CNUM 91
#define DETK 100
#define TOTALQ (NIMG * PNUM)
#define NEGV  -1000000000.0
#define NEGH  -500000000.0
#define CLAMP64 4.1351665567423558   // float64 nearest to log(1000/16)

// ---- workspace layout (bytes) ----
#define WS_ACT   0                          // f64 [32000]
#define WS_BH    (WS_ACT + TOTALQ * 8)      // f32 [4][32000] planar (clipped box hi)
#define WS_BL    (WS_BH  + TOTALQ * 16)     // f16 [4][32000] planar (box lo residual)
#define WS_LAB   (WS_BL  + TOTALQ * 8)      // u16 [32000]
#define WS_NEED  (WS_LAB + TOTALQ * 2)      // = 1,088,000 B

// =====================================================================
// Kernel A: one wave64 per proposal. Lane-parallel f64 softmax, fg
// argmax on raw logits (== prob argmax, first-occurrence ties), f64
// decode+clip+validity on lane 0.  (unchanged from round 4 — validated)
// =====================================================================
extern "C" __global__ __launch_bounds__(256)
void k_prep(const float* __restrict__ logits,
            const float* __restrict__ deltas,
            const float* __restrict__ props,
            double* __restrict__ w_act,
            float* __restrict__ w_bh,
            __half* __restrict__ w_bl,
            unsigned short* __restrict__ w_lab)
{
    const int wid  = blockIdx.x * 4 + (threadIdx.x >> 6);
    const int lane = threadIdx.x & 63;
    if (wid >= TOTALQ) return;

    const float* lg = logits + (long)wid * CNUM;
    const bool has1 = lane < (CNUM - 64);
    const float l0 = lg[lane];
    const float l1 = has1 ? lg[64 + lane] : 0.0f;

    float m = has1 ? fmaxf(l0, l1) : l0;
    #pragma unroll
    for (int s = 32; s; s >>= 1) m = fmaxf(m, __shfl_xor(m, s));

    const double e0 = exp((double)l0 - (double)m);
    const double e1 = has1 ? exp((double)l1 - (double)m) : 0.0;
    double sum = e0 + e1;
    #pragma unroll
    for (int s = 32; s; s >>= 1) sum += __shfl_xor(sum, s);

    float bv; int bc;
    if (lane >= 1) { bv = l0; bc = lane; } else { bv = -INFINITY; bc = 0x7fffffff; }
    if (has1 && l1 > bv) { bv = l1; bc = 64 + lane; }
    #pragma unroll
    for (int s = 32; s; s >>= 1) {
        const float ov = __shfl_xor(bv, s);
        const int   oc = __shfl_xor(bc, s);
        if (ov > bv || (ov == bv && oc < bc)) { bv = ov; bc = oc; }
    }

    if (lane == 0) {
        const int label = bc;
        const double score = exp((double)bv - (double)m) / sum;

        const float* pr = props + (long)wid * 4;
        const double x1p = (double)pr[0], y1p = (double)pr[1];
        const double x2p = (double)pr[2], y2p = (double)pr[3];
        const double w  = x2p - x1p, h = y2p - y1p;
        const double cx = x1p + 0.5 * w, cy = y1p + 0.5 * h;

        const float* dl = deltas + (long)wid * (CNUM * 4) + label * 4;
        const double dx = (double)dl[0] / 10.0;
        const double dy = (double)dl[1] / 10.0;
        const double dw = fmin((double)dl[2] / 5.0, CLAMP64);
        const double dh = fmin((double)dl[3] / 5.0, CLAMP64);

        const double pcx = dx * w + cx;
        const double pcy = dy * h + cy;
        const double pw  = exp(dw) * w;
        const double ph  = exp(dh) * h;

        double x1 = pcx - 0.5 * pw, y1 = pcy - 0.5 * ph;
        double x2 = pcx + 0.5 * pw, y2 = pcy + 0.5 * ph;
        x1 = fmin(fmax(x1, 0.0), 800.0);
        y1 = fmin(fmax(y1, 0.0), 800.0);
        x2 = fmin(fmax(x2, 0.0), 800.0);
        y2 = fmin(fmax(y2, 0.0), 800.0);

        const bool valid = ((x2 - x1) >= 0.01) && ((y2 - y1) >= 0.01) && (score > 0.05);

        w_act[wid] = valid ? score : NEGV;
        w_lab[wid] = (unsigned short)label;

        const float h0 = (float)x1, h1 = (float)y1, h2 = (float)x2, h3 = (float)y2;
        w_bh[0 * TOTALQ + wid] = h0;
        w_bh[1 * TOTALQ + wid] = h1;
        w_bh[2 * TOTALQ + wid] = h2;
        w_bh[3 * TOTALQ + wid] = h3;
        w_bl[0 * TOTALQ + wid] = __float2half((float)(x1 - (double)h0));
        w_bl[1 * TOTALQ + wid] = __float2half((float)(y1 - (double)h1));
        w_bl[2 * TOTALQ + wid] = __float2half((float)(x2 - (double)h2));
        w_bl[3 * TOTALQ + wid] = __float2half((float)(y2 - (double)h3));
    }
}

// =====================================================================
// Kernel B: one WAVE (64-thread block) per (image, label). Greedy NMS
// with zero barriers in the loop; candidates staged in LDS (f64).
// Suppressed entries get NEGV written back to w_act.
// =====================================================================
#define NMS_CAP 256

extern "C" __global__ __launch_bounds__(64)
void k_nms2(double* w_act,
            const float* __restrict__ w_bh,
            const __half* __restrict__ w_bl,
            const unsigned short* __restrict__ w_lab)
{
    __shared__ unsigned short ilist[63][64];                 // [slot_row][lane]
    __shared__ double ssc[NMS_CAP];
    __shared__ double sb0[NMS_CAP], sb1[NMS_CAP], sb2[NMS_CAP], sb3[NMS_CAP];

    const int img   = blockIdx.x / (CNUM - 1);
    const int label = 1 + (blockIdx.x % (CNUM - 1));
    const int lane  = threadIdx.x;
    const long base = (long)img * PNUM;

    // gather candidates of this label, striped across lanes
    int c = 0;
    for (int j = lane; j < PNUM; j += 64) {
        if ((int)w_lab[base + j] == label) {
            const double a = w_act[base + j];
            if (a > 0.0) {
                ilist[c][lane] = (unsigned short)j;
                const int slot = c * 64 + lane;
                if (slot < NMS_CAP) {
                    ssc[slot] = a;
                    sb0[slot] = (double)w_bh[0*TOTALQ + base + j] + (double)__half2float(w_bl[0*TOTALQ + base + j]);
                    sb1[slot] = (double)w_bh[1*TOTALQ + base + j] + (double)__half2float(w_bl[1*TOTALQ + base + j]);
                    sb2[slot] = (double)w_bh[2*TOTALQ + base + j] + (double)__half2float(w_bl[2*TOTALQ + base + j]);
                    sb3[slot] = (double)w_bh[3*TOTALQ + base + j] + (double)__half2float(w_bl[3*TOTALQ + base + j]);
                }
                ++c;
            }
        }
    }
    __syncthreads();   // make staged LDS visible to all lanes

    unsigned long long mask = (c >= 64) ? ~0ull : ((1ull << c) - 1ull);  // c <= 63

    for (;;) {
        // per-lane best among own active slots: (score desc, idx asc)
        double bs = -1.0; int bj = 0x7fffffff; int bslot = 0;
        for (int r = 0; r < c; ++r) if (mask & (1ull << r)) {
            const int j = ilist[r][lane];
            const int slot = r * 64 + lane;
            const double s = (slot < NMS_CAP) ? ssc[slot] : w_act[base + j];
            if (s > bs || (s == bs && j < bj)) { bs = s; bj = j; bslot = slot; }
        }
        // wave argmax
        #pragma unroll
        for (int sft = 32; sft; sft >>= 1) {
            const double os = __shfl_xor(bs, sft);
            const int    oj = __shfl_xor(bj, sft);
            const int    osl = __shfl_xor(bslot, sft);
            if (os > bs || (os == bs && oj < bj)) { bs = os; bj = oj; bslot = osl; }
        }
        if (bs <= 0.0) break;    // staged scores are all > 0.05

        // pick box (broadcast read — same address on all lanes)
        double px1, py1, px2, py2;
        if (bslot < NMS_CAP) {
            px1 = sb0[bslot]; py1 = sb1[bslot]; px2 = sb2[bslot]; py2 = sb3[bslot];
        } else {
            px1 = (double)w_bh[0*TOTALQ + base + bj] + (double)__half2float(w_bl[0*TOTALQ + base + bj]);
            py1 = (double)w_bh[1*TOTALQ + base + bj] + (double)__half2float(w_bl[1*TOTALQ + base + bj]);
            px2 = (double)w_bh[2*TOTALQ + base + bj] + (double)__half2float(w_bl[2*TOTALQ + base + bj]);
            py2 = (double)w_bh[3*TOTALQ + base + bj] + (double)__half2float(w_bl[3*TOTALQ + base + bj]);
        }
        const double a1 = (px2 - px1) * (py2 - py1);

        // winner keeps its score; clear its bit on the owning lane
        if ((bslot & 63) == lane) mask &= ~(1ull << (bslot >> 6));

        // suppression sweep (lane-parallel, no barriers)
        for (int r = 0; r < c; ++r) if (mask & (1ull << r)) {
            const int j = ilist[r][lane];
            const int slot = r * 64 + lane;
            double qx1, qy1, qx2, qy2;
            if (slot < NMS_CAP) {
                qx1 = sb0[slot]; qy1 = sb1[slot]; qx2 = sb2[slot]; qy2 = sb3[slot];
            } else {
                qx1 = (double)w_bh[0*TOTALQ + base + j] + (double)__half2float(w_bl[0*TOTALQ + base + j]);
                qy1 = (double)w_bh[1*TOTALQ + base + j] + (double)__half2float(w_bl[1*TOTALQ + base + j]);
                qx2 = (double)w_bh[2*TOTALQ + base + j] + (double)__half2float(w_bl[2*TOTALQ + base + j]);
                qy2 = (double)w_bh[3*TOTALQ + base + j] + (double)__half2float(w_bl[3*TOTALQ + base + j]);
            }
            const double ix = fmin(px2, qx2) - fmax(px1, qx1);
            const double iy = fmin(py2, qy2) - fmax(py1, qy1);
            const double inter = fmax(ix, 0.0) * fmax(iy, 0.0);
            const double a2  = (qx2 - qx1) * (qy2 - qy1);
            const double uni = fmax(a1 + a2 - inter, 1e-9);
            if (inter / uni > 0.5) { mask &= ~(1ull << r); w_act[base + j] = NEGV; }
        }
    }
}

// =====================================================================
// Kernel C: one block per image. Histogram-select the top-100 survivors
// by (f64 score desc, idx asc), exact small bitonic on the boundary set.
// =====================================================================
#define NBINS 2304

extern "C" __global__ __launch_bounds__(1024)
void k_topk(const double* __restrict__ w_act,
            const float* __restrict__ w_bh,
            const unsigned short* __restrict__ w_lab,
            float* __restrict__ out)
{
    __shared__ int hist[NBINS];
    __shared__ int csum[72];
    __shared__ int sT, scnt;
    __shared__ unsigned long long cKey[1024];
    __shared__ int cIdx[1024];

    const int n = blockIdx.x;
    const int tid = threadIdx.x;
    const long base = (long)n * PNUM;
    const unsigned long long KBASE = 0x3FA999999999999Aull >> 43;  // bits(0.05)>>43

    for (int i = tid; i < NBINS; i += 1024) hist[i] = 0;
    if (tid == 0) { sT = 0; scnt = 0; }
    __syncthreads();

    // histogram of survivor scores on top-21 bits (monotone for positive f64)
    for (int j = tid; j < PNUM; j += 1024) {
        const double a = w_act[base + j];
        if (a > 0.0) {
            const unsigned long long k = (unsigned long long)__double_as_longlong(a);
            int b = (int)((k >> 43) - KBASE);
            b = min(max(b, 0), NBINS - 1);
            atomicAdd(&hist[b], 1);
        }
    }
    __syncthreads();
    if (tid < 72) {
        int s = 0;
        #pragma unroll
        for (int b = 0; b < 32; ++b) s += hist[tid * 32 + b];
        csum[tid] = s;
    }
    __syncthreads();
    if (tid == 0) {
        int cum = 0, T = 0;
        for (int ch = 71; ch >= 0; --ch) {
            if (cum + csum[ch] >= DETK) {
                for (int b = ch * 32 + 31; b >= ch * 32; --b) {
                    cum += hist[b];
                    if (cum >= DETK) { T = b; break; }
                }
                break;
            }
            cum += csum[ch];
        }
        sT = T;    // stays 0 when fewer than 100 survivors
    }
    __syncthreads();
    const int T = sT;

    // compact candidates in bins >= T (order arbitrary; exact sort follows)
    for (int j = tid; j < PNUM; j += 1024) {
        const double a = w_act[base + j];
        if (a > 0.0) {
            const unsigned long long k = (unsigned long long)__double_as_longlong(a);
            int b = (int)((k >> 43) - KBASE);
            b = min(max(b, 0), NBINS - 1);
            if (b >= T) {
                const int p = atomicAdd(&scnt, 1);
                if (p < 1024) { cKey[p] = k; cIdx[p] = j; }
            }
        }
    }
    __syncthreads();
    const int cnt = min(scnt, 1024);
    int P = 128;
    while (P < cnt) P <<= 1;
    for (int i = tid; i < P; i += 1024) if (i >= cnt) { cKey[i] = 0ull; cIdx[i] = 0x7fffffff; }
    __syncthreads();

    // exact bitonic sort by (key desc, idx asc)
    for (int k2 = 2; k2 <= P; k2 <<= 1) {
        for (int j2 = k2 >> 1; j2 > 0; j2 >>= 1) {
            if (tid < P) {
                const int i = tid;
                const int p = i ^ j2;
                if (p > i) {
                    const unsigned long long ka = cKey[i], kb = cKey[p];
                    const int ia = cIdx[i], ib = cIdx[p];
                    const bool aFirst = (ka > kb) || (ka == kb && ia < ib);
                    const bool up = ((i & k2) == 0);
                    if (up ? !aFirst : aFirst) {
                        cKey[i] = kb; cKey[p] = ka;
                        cIdx[i] = ib; cIdx[p] = ia;
                    }
                }
            }
            __syncthreads();
        }
    }

    // emit top-100 (pad with zeros when < 100 survivors)
    if (tid < DETK) {
        const int o = n * DETK + tid;
        const bool kp = (tid < cnt) && (cKey[tid] != 0ull);
        float lab = 0.f, sc = 0.f, b0 = 0.f, b1 = 0.f, b2 = 0.f, b3 = 0.f;
        if (kp) {
            const int idx = cIdx[tid];
            lab = (float)w_lab[base + idx];
            sc  = (float)__longlong_as_double((long long)cKey[tid]);
            b0 = w_bh[0 * TOTALQ + base + idx];    // hi part == (float)x64 exactly
            b1 = w_bh[1 * TOTALQ + base + idx];
            b2 = w_bh[2 * TOTALQ + base + idx];
            b3 = w_bh[3 * TOTALQ + base + idx];
        }
        out[o]               = lab;
        out[NIMG * DETK + o] = sc;
        out[2 * NIMG * DETK + o * 4 + 0] = b0;
        out[2 * NIMG * DETK + o * 4 + 1] = b1;
        out[2 * NIMG * DETK + o * 4 + 2] = b2;
        out[2 * NIMG * DETK + o * 4 + 3] = b3;
    }
}

// =====================================================================
// Fallback (proven round-3 kernel) in case ws_size < WS_NEED.
// =====================================================================
extern "C" __global__ __launch_bounds__(1024)
void k_fused(const float* __restrict__ logits,
             const float* __restrict__ deltas,
             const float* __restrict__ props,
             float* __restrict__ out)
{
    __shared__ float   bh0[PNUM], bh1[PNUM], bh2[PNUM], bh3[PNUM];
    __shared__ __half  bl0[PNUM], bl1[PNUM], bl2[PNUM], bl3[PNUM];
    __shared__ double  act[PNUM];
    __shared__ unsigned short slab[PNUM];
    __shared__ double  redV[16];
    __shared__ int     redI[16];
    __shared__ double  pbox[4];
    __shared__ int     pidx, pkeep, plab;
    __shared__ int     kidx[DETK], kkeep[DETK];
    __shared__ double  kscore[DETK];
    __shared__ double  kbox[DETK][4];

    const int n   = blockIdx.x;
    const int tid = threadIdx.x;

    for (int j = tid; j < PNUM; j += 1024) {
        const long q = (long)n * PNUM + j;
        const float* lg = logits + q * CNUM;
        float ml = lg[0];
        float bv = lg[1];
        int   lab = 1;
        for (int c = 1; c < CNUM; ++c) {
            const float v = lg[c];
            ml = fmaxf(ml, v);
            if (c >= 2 && v > bv) { bv = v; lab = c; }
        }
        const double m = (double)ml;
        double sum = 0.0;
        for (int c = 0; c < CNUM; ++c) sum += exp((double)lg[c] - m);
        const double score = exp((double)bv - m) / sum;

        const float* pr = props + q * 4;
        const double x1p = (double)pr[0], y1p = (double)pr[1];
        const double x2p = (double)pr[2], y2p = (double)pr[3];
        const double w  = x2p - x1p, h = y2p - y1p;
        const double cx = x1p + 0.5 * w, cy = y1p + 0.5 * h;
        const float* dl = deltas + q * (CNUM * 4) + lab * 4;
        const double dx = (double)dl[0] / 10.0;
        const double dy = (double)dl[1] / 10.0;
        const double dw = fmin((double)dl[2] / 5.0, CLAMP64);
        const double dh = fmin((double)dl[3] / 5.0, CLAMP64);
        const double pcx = dx * w + cx;
        const double pcy = dy * h + cy;
        const double pw  = exp(dw) * w;
        const double ph  = exp(dh) * h;
        double x1 = pcx - 0.5 * pw, y1 = pcy - 0.5 * ph;
        double x2 = pcx + 0.5 * pw, y2 = pcy + 0.5 * ph;
        x1 = fmin(fmax(x1, 0.0), 800.0);
        y1 = fmin(fmax(y1, 0.0), 800.0);
        x2 = fmin(fmax(x2, 0.0), 800.0);
        y2 = fmin(fmax(y2, 0.0), 800.0);
        const bool valid = ((x2 - x1) >= 0.01) && ((y2 - y1) >= 0.01) && (score > 0.05);
        act[j]  = valid ? score : NEGV;
        slab[j] = (unsigned short)lab;
        const float h0 = (float)x1, h1 = (float)y1, h2 = (float)x2, h3 = (float)y2;
        bh0[j] = h0; bh1[j] = h1; bh2[j] = h2; bh3[j] = h3;
        bl0[j] = __float2half((float)(x1 - (double)h0));
        bl1[j] = __float2half((float)(y1 - (double)h1));
        bl2[j] = __float2half((float)(x2 - (double)h2));
        bl3[j] = __float2half((float)(y2 - (double)h3));
    }
    __syncthreads();

    for (int k = 0; k < DETK; ++k) {
        double bv = -INFINITY;
        int    bi = 0x7fffffff;
        #pragma unroll
        for (int t = 0; t < 4; ++t) {
            const int j = tid + t * 1024;
            if (j < PNUM) {
                const double v = act[j];
                if (v > bv) { bv = v; bi = j; }
            }
        }
        #pragma unroll
        for (int s = 32; s; s >>= 1) {
            const double ov = __shfl_xor(bv, s);
            const int    oi = __shfl_xor(bi, s);
            if (ov > bv || (ov == bv && oi < bi)) { bv = ov; bi = oi; }
        }
        if ((tid & 63) == 0) { redV[tid >> 6] = bv; redI[tid >> 6] = bi; }
        __syncthreads();
        if (tid < 64) {
            bv = (tid < 16) ? redV[tid] : -INFINITY;
            bi = (tid < 16) ? redI[tid] : 0x7fffffff;
            #pragma unroll
            for (int s = 8; s; s >>= 1) {
                const double ov = __shfl_xor(bv, s);
                const int    oi = __shfl_xor(bi, s);
                if (ov > bv || (ov == bv && oi < bi)) { bv = ov; bi = oi; }
            }
            if (tid == 0) {
                const int kp = (bv > NEGH) ? 1 : 0;
                pidx = bi; pkeep = kp; plab = (int)slab[bi];
                kidx[k] = bi; kkeep[k] = kp; kscore[k] = bv;
                const double b0 = (double)bh0[bi] + (double)__half2float(bl0[bi]);
                const double b1 = (double)bh1[bi] + (double)__half2float(bl1[bi]);
                const double b2 = (double)bh2[bi] + (double)__half2float(bl2[bi]);
                const double b3 = (double)bh3[bi] + (double)__half2float(bl3[bi]);
                pbox[0] = b0; pbox[1] = b1; pbox[2] = b2; pbox[3] = b3;
                kbox[k][0] = b0; kbox[k][1] = b1; kbox[k][2] = b2; kbox[k][3] = b3;
            }
        }
        __syncthreads();

        const int    pick = pidx;
        const int    kp   = pkeep;
        const int    pl   = plab;
        const double px1 = pbox[0], py1 = pbox[1], px2 = pbox[2], py2 = pbox[3];
        const double a1  = (px2 - px1) * (py2 - py1);
        #pragma unroll
        for (int t = 0; t < 4; ++t) {
            const int j = tid + t * 1024;
            if (j >= PNUM) break;
            if (j == pick) { act[j] = NEGV; continue; }
            if (!kp) continue;
            if ((int)slab[j] != pl) continue;
            if (act[j] <= NEGH) continue;
            const double qx1 = (double)bh0[j] + (double)__half2float(bl0[j]);
            const double qy1 = (double)bh1[j] + (double)__half2float(bl1[j]);
            const double qx2 = (double)bh2[j] + (double)__half2float(bl2[j]);
            const double qy2 = (double)bh3[j] + (double)__half2float(bl3[j]);
            const double ix = fmin(px2, qx2) - fmax(px1, qx1);
            const double iy = fmin(py2, qy2) - fmax(py1, qy1);
            const double inter = fmax(ix, 0.0) * fmax(iy, 0.0);
            const double a2  = (qx2 - qx1) * (qy2 - qy1);
            const double uni = fmax(a1 + a2 - inter, 1e-9);
            if (inter / uni > 0.5) act[j] = NEGV;
        }
        __syncthreads();
    }

    if (tid < DETK) {
        const int kp = kkeep[tid];
        const int o  = n * DETK + tid;
        out[o]               = kp ? (float)slab[kidx[tid]] : 0.0f;
        out[NIMG * DETK + o] = kp ? (float)kscore[tid] : 0.0f;
        #pragma unroll
        for (int i = 0; i < 4; ++i)
            out[2 * NIMG * DETK + o * 4 + i] = kp ? (float)kbox[tid][i] : 0.0f;
    }
}

extern "C" void kernel_launch(void* const* d_in, const int* in_sizes, int n_in,
                              void* d_out, int out_size, void* d_ws, size_t ws_size,
                              hipStream_t stream)
{
    const float* logits = (const float*)d_in[1];
    const float* deltas = (const float*)d_in[2];
    const float* props  = (const float*)d_in[3];
    float* out = (float*)d_out;

    if (ws_size >= (size_t)WS_NEED) {
        char* ws = (char*)d_ws;
        double*         w_act = (double*)(ws + WS_ACT);
        float*          w_bh  = (float*)(ws + WS_BH);
        __half*         w_bl  = (__half*)(ws + WS_BL);
        unsigned short* w_lab = (unsigned short*)(ws + WS_LAB);

        hipLaunchKernelGGL(k_prep, dim3(TOTALQ / 4), dim3(256), 0, stream,
                           logits, deltas, props, w_act, w_bh, w_bl, w_lab);
        hipLaunchKernelGGL(k_nms2, dim3(NIMG * (CNUM - 1)), dim3(64), 0, stream,
                           w_act, w_bh, w_bl, w_lab);
        hipLaunchKernelGGL(k_topk, dim3(NIMG), dim3(1024), 0, stream,
                           w_act, w_bh, w_lab, out);
    } else {
        hipLaunchKernelGGL(k_fused, dim3(NIMG), dim3(1024), 0, stream,
                           logits, deltas, props, out);
    }
}

// Round 6
// 113.830 us; speedup vs baseline: 4.5039x; 2.1863x over previous
//
#include <hip/hip_runtime.h>
#include <hip/hip_fp16.h>
#include <math.h>

#define NIMG 8
#define PNUM 4000
#define CNUM 91
#define DETK 100
#define TOTALQ (NIMG * PNUM)
#define NEGV  -1000000000.0
#define NEGH  -500000000.0
#define CLAMP64 4.1351665567423558   // float64 nearest to log(1000/16)

// ---- workspace layout (bytes) ----
#define WS_ACT   0                          // f64 [32000]
#define WS_BH    (WS_ACT + TOTALQ * 8)      // f32 [4][32000] planar (clipped box hi)
#define WS_BL    (WS_BH  + TOTALQ * 16)     // f16 [4][32000] planar (box lo residual)
#define WS_LAB   (WS_BL  + TOTALQ * 8)      // u16 [32000]
#define WS_NEED  (WS_LAB + TOTALQ * 2)      // = 1,088,000 B

// =====================================================================
// Kernel A: one wave64 per proposal. Lane-parallel f64 softmax, fg
// argmax on raw logits (== prob argmax, first-occurrence ties), f64
// decode+clip+validity on lane 0.  (validated rounds 4-5)
// =====================================================================
extern "C" __global__ __launch_bounds__(256)
void k_prep(const float* __restrict__ logits,
            const float* __restrict__ deltas,
            const float* __restrict__ props,
            double* __restrict__ w_act,
            float* __restrict__ w_bh,
            __half* __restrict__ w_bl,
            unsigned short* __restrict__ w_lab)
{
    const int wid  = blockIdx.x * 4 + (threadIdx.x >> 6);
    const int lane = threadIdx.x & 63;
    if (wid >= TOTALQ) return;

    const float* lg = logits + (long)wid * CNUM;
    const bool has1 = lane < (CNUM - 64);
    const float l0 = lg[lane];
    const float l1 = has1 ? lg[64 + lane] : 0.0f;

    float m = has1 ? fmaxf(l0, l1) : l0;
    #pragma unroll
    for (int s = 32; s; s >>= 1) m = fmaxf(m, __shfl_xor(m, s));

    const double e0 = exp((double)l0 - (double)m);
    const double e1 = has1 ? exp((double)l1 - (double)m) : 0.0;
    double sum = e0 + e1;
    #pragma unroll
    for (int s = 32; s; s >>= 1) sum += __shfl_xor(sum, s);

    float bv; int bc;
    if (lane >= 1) { bv = l0; bc = lane; } else { bv = -INFINITY; bc = 0x7fffffff; }
    if (has1 && l1 > bv) { bv = l1; bc = 64 + lane; }
    #pragma unroll
    for (int s = 32; s; s >>= 1) {
        const float ov = __shfl_xor(bv, s);
        const int   oc = __shfl_xor(bc, s);
        if (ov > bv || (ov == bv && oc < bc)) { bv = ov; bc = oc; }
    }

    if (lane == 0) {
        const int label = bc;
        const double score = exp((double)bv - (double)m) / sum;

        const float* pr = props + (long)wid * 4;
        const double x1p = (double)pr[0], y1p = (double)pr[1];
        const double x2p = (double)pr[2], y2p = (double)pr[3];
        const double w  = x2p - x1p, h = y2p - y1p;
        const double cx = x1p + 0.5 * w, cy = y1p + 0.5 * h;

        const float* dl = deltas + (long)wid * (CNUM * 4) + label * 4;
        const double dx = (double)dl[0] / 10.0;
        const double dy = (double)dl[1] / 10.0;
        const double dw = fmin((double)dl[2] / 5.0, CLAMP64);
        const double dh = fmin((double)dl[3] / 5.0, CLAMP64);

        const double pcx = dx * w + cx;
        const double pcy = dy * h + cy;
        const double pw  = exp(dw) * w;
        const double ph  = exp(dh) * h;

        double x1 = pcx - 0.5 * pw, y1 = pcy - 0.5 * ph;
        double x2 = pcx + 0.5 * pw, y2 = pcy + 0.5 * ph;
        x1 = fmin(fmax(x1, 0.0), 800.0);
        y1 = fmin(fmax(y1, 0.0), 800.0);
        x2 = fmin(fmax(x2, 0.0), 800.0);
        y2 = fmin(fmax(y2, 0.0), 800.0);

        const bool valid = ((x2 - x1) >= 0.01) && ((y2 - y1) >= 0.01) && (score > 0.05);

        w_act[wid] = valid ? score : NEGV;
        w_lab[wid] = (unsigned short)label;

        const float h0 = (float)x1, h1 = (float)y1, h2 = (float)x2, h3 = (float)y2;
        w_bh[0 * TOTALQ + wid] = h0;
        w_bh[1 * TOTALQ + wid] = h1;
        w_bh[2 * TOTALQ + wid] = h2;
        w_bh[3 * TOTALQ + wid] = h3;
        w_bl[0 * TOTALQ + wid] = __float2half((float)(x1 - (double)h0));
        w_bl[1 * TOTALQ + wid] = __float2half((float)(y1 - (double)h1));
        w_bl[2 * TOTALQ + wid] = __float2half((float)(x2 - (double)h2));
        w_bl[3 * TOTALQ + wid] = __float2half((float)(y2 - (double)h3));
    }
}

// =====================================================================
// Kernel B (new): one wave per (image,label). Matrix-NMS == greedy-NMS:
// rank by (score desc, idx asc) via O(n^2/64) counting (no sort net),
// wave-parallel f64 IoU bit-rows, one short serial resolve. No per-pick
// argmax chains. Suppressed entries write NEGV back to w_act.
// =====================================================================
#define NCAP 256

extern "C" __global__ __launch_bounds__(64)
void k_nms3(double* w_act,
            const float* __restrict__ w_bh,
            const __half* __restrict__ w_bl,
            const unsigned short* __restrict__ w_lab)
{
    __shared__ int s_n;
    __shared__ unsigned long long skey[NCAP];
    __shared__ int sj[NCAP];
    __shared__ double sx1[NCAP], sy1[NCAP], sx2[NCAP], sy2[NCAP];
    __shared__ unsigned short perm[NCAP];           // sorted pos -> slot
    __shared__ unsigned long long rows[NCAP][4];    // suppression bit-rows

    const int img   = blockIdx.x / (CNUM - 1);
    const int label = 1 + (blockIdx.x % (CNUM - 1));
    const int lane  = threadIdx.x;
    const long base = (long)img * PNUM;

    if (lane == 0) s_n = 0;
    __syncthreads();

    // ---- vectorized label scan (u16 x4), candidates -> LDS slots ----
    for (int r = 0; r < (PNUM + 255) / 256; ++r) {
        const int j0 = r * 256 + lane * 4;
        if (j0 < PNUM) {
            const ushort4 l4 = *reinterpret_cast<const ushort4*>(&w_lab[base + j0]);
            const unsigned short ls0 = l4.x, ls1 = l4.y, ls2 = l4.z, ls3 = l4.w;
            #pragma unroll
            for (int t = 0; t < 4; ++t) {
                const int j = j0 + t;
                const unsigned short lb = (t == 0) ? ls0 : (t == 1) ? ls1 : (t == 2) ? ls2 : ls3;
                if (j < PNUM && (int)lb == label) {
                    const double a = w_act[base + j];
                    if (a > 0.0) {
                        const int s = atomicAdd(&s_n, 1);
                        if (s < NCAP) {
                            skey[s] = (unsigned long long)__double_as_longlong(a);
                            sj[s]   = j;
                            sx1[s] = (double)w_bh[0*TOTALQ + base + j] + (double)__half2float(w_bl[0*TOTALQ + base + j]);
                            sy1[s] = (double)w_bh[1*TOTALQ + base + j] + (double)__half2float(w_bl[1*TOTALQ + base + j]);
                            sx2[s] = (double)w_bh[2*TOTALQ + base + j] + (double)__half2float(w_bl[2*TOTALQ + base + j]);
                            sy2[s] = (double)w_bh[3*TOTALQ + base + j] + (double)__half2float(w_bl[3*TOTALQ + base + j]);
                        }
                    }
                }
            }
        }
    }
    __syncthreads();
    const int n = min(s_n, NCAP);
    if (n <= 1) return;                 // 0/1 candidates: nothing to suppress

    // ---- rank by (key desc, j asc); ranks unique since j distinct ----
    for (int s = lane; s < n; s += 64) {
        const unsigned long long ks = skey[s];
        const int js = sj[s];
        int rank = 0;
        for (int q = 0; q < n; ++q) {
            const unsigned long long kq = skey[q];
            rank += (int)((kq > ks) || (kq == ks && sj[q] < js));
        }
        perm[rank] = (unsigned short)s;
    }
    __syncthreads();

    // ---- IoU bit-rows per sorted position (wave-parallel, f64) ----
    for (int p = lane; p < n; p += 64) {
        const int sp = perm[p];
        const double px1 = sx1[sp], py1 = sy1[sp], px2 = sx2[sp], py2 = sy2[sp];
        const double a1 = (px2 - px1) * (py2 - py1);
        #pragma unroll
        for (int w = 0; w < 4; ++w) {           // static word index (no scratch)
            unsigned long long rw = 0;
            if (w * 64 < n) {
                const int qhi = min(n, w * 64 + 64);
                for (int q = w * 64; q < qhi; ++q) {
                    if (q == p) continue;
                    const int sq = perm[q];
                    const double qx1 = sx1[sq], qy1 = sy1[sq];
                    const double qx2 = sx2[sq], qy2 = sy2[sq];
                    const double ix = fmin(px2, qx2) - fmax(px1, qx1);
                    const double iy = fmin(py2, qy2) - fmax(py1, qy1);
                    const double inter = fmax(ix, 0.0) * fmax(iy, 0.0);
                    const double a2  = (qx2 - qx1) * (qy2 - qy1);
                    const double uni = fmax(a1 + a2 - inter, 1e-9);
                    if (inter / uni > 0.5) rw |= (1ull << (q & 63));
                }
            }
            rows[p][w] = rw;
        }
    }
    __syncthreads();

    // ---- serial greedy resolve (all lanes redundant; LDS broadcast reads) ----
    unsigned long long s0 = 0, s1 = 0, s2 = 0, s3 = 0;
    for (int i = 0; i < n; ++i) {
        const int w = i >> 6, b = i & 63;
        const unsigned long long sw = (w == 0) ? s0 : (w == 1) ? s1 : (w == 2) ? s2 : s3;
        if (!((sw >> b) & 1ull)) {              // i is KEPT -> OR its row
            s0 |= rows[i][0];
            s1 |= rows[i][1];
            s2 |= rows[i][2];
            s3 |= rows[i][3];
        }
    }

    // ---- write back suppressed ----
    for (int p = lane; p < n; p += 64) {
        const int w = p >> 6, b = p & 63;
        const unsigned long long sw = (w == 0) ? s0 : (w == 1) ? s1 : (w == 2) ? s2 : s3;
        if ((sw >> b) & 1ull)
            w_act[base + sj[perm[p]]] = NEGV;
    }
}

// =====================================================================
// Kernel C: one block per image. Histogram-select top-100 survivors by
// (f64 score desc, idx asc), exact small bitonic on boundary set.
// (validated round 5)
// =====================================================================
#define NBINS 2304

extern "C" __global__ __launch_bounds__(1024)
void k_topk(const double* __restrict__ w_act,
            const float* __restrict__ w_bh,
            const unsigned short* __restrict__ w_lab,
            float* __restrict__ out)
{
    __shared__ int hist[NBINS];
    __shared__ int csum[72];
    __shared__ int sT, scnt;
    __shared__ unsigned long long cKey[1024];
    __shared__ int cIdx[1024];

    const int n = blockIdx.x;
    const int tid = threadIdx.x;
    const long base = (long)n * PNUM;
    const unsigned long long KBASE = 0x3FA999999999999Aull >> 43;

    for (int i = tid; i < NBINS; i += 1024) hist[i] = 0;
    if (tid == 0) { sT = 0; scnt = 0; }
    __syncthreads();

    for (int j = tid; j < PNUM; j += 1024) {
        const double a = w_act[base + j];
        if (a > 0.0) {
            const unsigned long long k = (unsigned long long)__double_as_longlong(a);
            int b = (int)((k >> 43) - KBASE);
            b = min(max(b, 0), NBINS - 1);
            atomicAdd(&hist[b], 1);
        }
    }
    __syncthreads();
    if (tid < 72) {
        int s = 0;
        #pragma unroll
        for (int b = 0; b < 32; ++b) s += hist[tid * 32 + b];
        csum[tid] = s;
    }
    __syncthreads();
    if (tid == 0) {
        int cum = 0, T = 0;
        for (int ch = 71; ch >= 0; --ch) {
            if (cum + csum[ch] >= DETK) {
                for (int b = ch * 32 + 31; b >= ch * 32; --b) {
                    cum += hist[b];
                    if (cum >= DETK) { T = b; break; }
                }
                break;
            }
            cum += csum[ch];
        }
        sT = T;
    }
    __syncthreads();
    const int T = sT;

    for (int j = tid; j < PNUM; j += 1024) {
        const double a = w_act[base + j];
        if (a > 0.0) {
            const unsigned long long k = (unsigned long long)__double_as_longlong(a);
            int b = (int)((k >> 43) - KBASE);
            b = min(max(b, 0), NBINS - 1);
            if (b >= T) {
                const int p = atomicAdd(&scnt, 1);
                if (p < 1024) { cKey[p] = k; cIdx[p] = j; }
            }
        }
    }
    __syncthreads();
    const int cnt = min(scnt, 1024);
    int P = 128;
    while (P < cnt) P <<= 1;
    for (int i = tid; i < P; i += 1024) if (i >= cnt) { cKey[i] = 0ull; cIdx[i] = 0x7fffffff; }
    __syncthreads();

    for (int k2 = 2; k2 <= P; k2 <<= 1) {
        for (int j2 = k2 >> 1; j2 > 0; j2 >>= 1) {
            if (tid < P) {
                const int i = tid;
                const int p = i ^ j2;
                if (p > i) {
                    const unsigned long long ka = cKey[i], kb = cKey[p];
                    const int ia = cIdx[i], ib = cIdx[p];
                    const bool aFirst = (ka > kb) || (ka == kb && ia < ib);
                    const bool up = ((i & k2) == 0);
                    if (up ? !aFirst : aFirst) {
                        cKey[i] = kb; cKey[p] = ka;
                        cIdx[i] = ib; cIdx[p] = ia;
                    }
                }
            }
            __syncthreads();
        }
    }

    if (tid < DETK) {
        const int o = n * DETK + tid;
        const bool kp = (tid < cnt) && (cKey[tid] != 0ull);
        float lab = 0.f, sc = 0.f, b0 = 0.f, b1 = 0.f, b2 = 0.f, b3 = 0.f;
        if (kp) {
            const int idx = cIdx[tid];
            lab = (float)w_lab[base + idx];
            sc  = (float)__longlong_as_double((long long)cKey[tid]);
            b0 = w_bh[0 * TOTALQ + base + idx];
            b1 = w_bh[1 * TOTALQ + base + idx];
            b2 = w_bh[2 * TOTALQ + base + idx];
            b3 = w_bh[3 * TOTALQ + base + idx];
        }
        out[o]               = lab;
        out[NIMG * DETK + o] = sc;
        out[2 * NIMG * DETK + o * 4 + 0] = b0;
        out[2 * NIMG * DETK + o * 4 + 1] = b1;
        out[2 * NIMG * DETK + o * 4 + 2] = b2;
        out[2 * NIMG * DETK + o * 4 + 3] = b3;
    }
}

// =====================================================================
// Fallback (proven round-3 kernel) in case ws_size < WS_NEED.
// =====================================================================
extern "C" __global__ __launch_bounds__(1024)
void k_fused(const float* __restrict__ logits,
             const float* __restrict__ deltas,
             const float* __restrict__ props,
             float* __restrict__ out)
{
    __shared__ float   bh0[PNUM], bh1[PNUM], bh2[PNUM], bh3[PNUM];
    __shared__ __half  bl0[PNUM], bl1[PNUM], bl2[PNUM], bl3[PNUM];
    __shared__ double  act[PNUM];
    __shared__ unsigned short slab[PNUM];
    __shared__ double  redV[16];
    __shared__ int     redI[16];
    __shared__ double  pbox[4];
    __shared__ int     pidx, pkeep, plab;
    __shared__ int     kidx[DETK], kkeep[DETK];
    __shared__ double  kscore[DETK];
    __shared__ double  kbox[DETK][4];

    const int n   = blockIdx.x;
    const int tid = threadIdx.x;

    for (int j = tid; j < PNUM; j += 1024) {
        const long q = (long)n * PNUM + j;
        const float* lg = logits + q * CNUM;
        float ml = lg[0];
        float bv = lg[1];
        int   lab = 1;
        for (int c = 1; c < CNUM; ++c) {
            const float v = lg[c];
            ml = fmaxf(ml, v);
            if (c >= 2 && v > bv) { bv = v; lab = c; }
        }
        const double m = (double)ml;
        double sum = 0.0;
        for (int c = 0; c < CNUM; ++c) sum += exp((double)lg[c] - m);
        const double score = exp((double)bv - m) / sum;

        const float* pr = props + q * 4;
        const double x1p = (double)pr[0], y1p = (double)pr[1];
        const double x2p = (double)pr[2], y2p = (double)pr[3];
        const double w  = x2p - x1p, h = y2p - y1p;
        const double cx = x1p + 0.5 * w, cy = y1p + 0.5 * h;
        const float* dl = deltas + q * (CNUM * 4) + lab * 4;
        const double dx = (double)dl[0] / 10.0;
        const double dy = (double)dl[1] / 10.0;
        const double dw = fmin((double)dl[2] / 5.0, CLAMP64);
        const double dh = fmin((double)dl[3] / 5.0, CLAMP64);
        const double pcx = dx * w + cx;
        const double pcy = dy * h + cy;
        const double pw  = exp(dw) * w;
        const double ph  = exp(dh) * h;
        double x1 = pcx - 0.5 * pw, y1 = pcy - 0.5 * ph;
        double x2 = pcx + 0.5 * pw, y2 = pcy + 0.5 * ph;
        x1 = fmin(fmax(x1, 0.0), 800.0);
        y1 = fmin(fmax(y1, 0.0), 800.0);
        x2 = fmin(fmax(x2, 0.0), 800.0);
        y2 = fmin(fmax(y2, 0.0), 800.0);
        const bool valid = ((x2 - x1) >= 0.01) && ((y2 - y1) >= 0.01) && (score > 0.05);
        act[j]  = valid ? score : NEGV;
        slab[j] = (unsigned short)lab;
        const float h0 = (float)x1, h1 = (float)y1, h2 = (float)x2, h3 = (float)y2;
        bh0[j] = h0; bh1[j] = h1; bh2[j] = h2; bh3[j] = h3;
        bl0[j] = __float2half((float)(x1 - (double)h0));
        bl1[j] = __float2half((float)(y1 - (double)h1));
        bl2[j] = __float2half((float)(x2 - (double)h2));
        bl3[j] = __float2half((float)(y2 - (double)h3));
    }
    __syncthreads();

    for (int k = 0; k < DETK; ++k) {
        double bv = -INFINITY;
        int    bi = 0x7fffffff;
        #pragma unroll
        for (int t = 0; t < 4; ++t) {
            const int j = tid + t * 1024;
            if (j < PNUM) {
                const double v = act[j];
                if (v > bv) { bv = v; bi = j; }
            }
        }
        #pragma unroll
        for (int s = 32; s; s >>= 1) {
            const double ov = __shfl_xor(bv, s);
            const int    oi = __shfl_xor(bi, s);
            if (ov > bv || (ov == bv && oi < bi)) { bv = ov; bi = oi; }
        }
        if ((tid & 63) == 0) { redV[tid >> 6] = bv; redI[tid >> 6] = bi; }
        __syncthreads();
        if (tid < 64) {
            bv = (tid < 16) ? redV[tid] : -INFINITY;
            bi = (tid < 16) ? redI[tid] : 0x7fffffff;
            #pragma unroll
            for (int s = 8; s; s >>= 1) {
                const double ov = __shfl_xor(bv, s);
                const int    oi = __shfl_xor(bi, s);
                if (ov > bv || (ov == bv && oi < bi)) { bv = ov; bi = oi; }
            }
            if (tid == 0) {
                const int kp = (bv > NEGH) ? 1 : 0;
                pidx = bi; pkeep = kp; plab = (int)slab[bi];
                kidx[k] = bi; kkeep[k] = kp; kscore[k] = bv;
                const double b0 = (double)bh0[bi] + (double)__half2float(bl0[bi]);
                const double b1 = (double)bh1[bi] + (double)__half2float(bl1[bi]);
                const double b2 = (double)bh2[bi] + (double)__half2float(bl2[bi]);
                const double b3 = (double)bh3[bi] + (double)__half2float(bl3[bi]);
                pbox[0] = b0; pbox[1] = b1; pbox[2] = b2; pbox[3] = b3;
                kbox[k][0] = b0; kbox[k][1] = b1; kbox[k][2] = b2; kbox[k][3] = b3;
            }
        }
        __syncthreads();

        const int    pick = pidx;
        const int    kp   = pkeep;
        const int    pl   = plab;
        const double px1 = pbox[0], py1 = pbox[1], px2 = pbox[2], py2 = pbox[3];
        const double a1  = (px2 - px1) * (py2 - py1);
        #pragma unroll
        for (int t = 0; t < 4; ++t) {
            const int j = tid + t * 1024;
            if (j >= PNUM) break;
            if (j == pick) { act[j] = NEGV; continue; }
            if (!kp) continue;
            if ((int)slab[j] != pl) continue;
            if (act[j] <= NEGH) continue;
            const double qx1 = (double)bh0[j] + (double)__half2float(bl0[j]);
            const double qy1 = (double)bh1[j] + (double)__half2float(bl1[j]);
            const double qx2 = (double)bh2[j] + (double)__half2float(bl2[j]);
            const double qy2 = (double)bh3[j] + (double)__half2float(bl3[j]);
            const double ix = fmin(px2, qx2) - fmax(px1, qx1);
            const double iy = fmin(py2, qy2) - fmax(py1, qy1);
            const double inter = fmax(ix, 0.0) * fmax(iy, 0.0);
            const double a2  = (qx2 - qx1) * (qy2 - qy1);
            const double uni = fmax(a1 + a2 - inter, 1e-9);
            if (inter / uni > 0.5) act[j] = NEGV;
        }
        __syncthreads();
    }

    if (tid < DETK) {
        const int kp = kkeep[tid];
        const int o  = n * DETK + tid;
        out[o]               = kp ? (float)slab[kidx[tid]] : 0.0f;
        out[NIMG * DETK + o] = kp ? (float)kscore[tid] : 0.0f;
        #pragma unroll
        for (int i = 0; i < 4; ++i)
            out[2 * NIMG * DETK + o * 4 + i] = kp ? (float)kbox[tid][i] : 0.0f;
    }
}

extern "C" void kernel_launch(void* const* d_in, const int* in_sizes, int n_in,
                              void* d_out, int out_size, void* d_ws, size_t ws_size,
                              hipStream_t stream)
{
    const float* logits = (const float*)d_in[1];
    const float* deltas = (const float*)d_in[2];
    const float* props  = (const float*)d_in[3];
    float* out = (float*)d_out;

    if (ws_size >= (size_t)WS_NEED) {
        char* ws = (char*)d_ws;
        double*         w_act = (double*)(ws + WS_ACT);
        float*          w_bh  = (float*)(ws + WS_BH);
        __half*         w_bl  = (__half*)(ws + WS_BL);
        unsigned short* w_lab = (unsigned short*)(ws + WS_LAB);

        hipLaunchKernelGGL(k_prep, dim3(TOTALQ / 4), dim3(256), 0, stream,
                           logits, deltas, props, w_act, w_bh, w_bl, w_lab);
        hipLaunchKernelGGL(k_nms3, dim3(NIMG * (CNUM - 1)), dim3(64), 0, stream,
                           w_act, w_bh, w_bl, w_lab);
        hipLaunchKernelGGL(k_topk, dim3(NIMG), dim3(1024), 0, stream,
                           w_act, w_bh, w_lab, out);
    } else {
        hipLaunchKernelGGL(k_fused, dim3(NIMG), dim3(1024), 0, stream,
                           logits, deltas, props, out);
    }
}

// Round 7
// 99.519 us; speedup vs baseline: 5.1516x; 1.1438x over previous
//
#include <hip/hip_runtime.h>
#include <hip/hip_fp16.h>
#include <math.h>

#define NIMG 8
#define PNUM 4000
#define CNUM 91
#define DETK 100
#define TOTALQ (NIMG * PNUM)
#define NEGV  -1000000000.0
#define NEGH  -500000000.0
#define CLAMP64 4.1351665567423558   // float64 nearest to log(1000/16)

// ---- workspace layout (bytes) ----
#define WS_ACT   0                          // f64 [32000]
#define WS_BH4   (WS_ACT + TOTALQ * 8)      // float4 [32000] interleaved box hi
#define WS_BL2   (WS_BH4 + TOTALQ * 16)     // __half2 [2][32000] interleaved box lo
#define WS_LAB   (WS_BL2 + TOTALQ * 8)      // u16 [32000]
#define WS_NEED  (WS_LAB + TOTALQ * 2)      // = 1,088,000 B

typedef __attribute__((ext_vector_type(8))) unsigned short u16x8;

__device__ __forceinline__ float h2f_bits(unsigned int u) {
    __half_raw r; r.x = (unsigned short)u;
    return __half2float(__half(r));
}

// =====================================================================
// Kernel A: one wave64 per proposal. Lane-parallel f64 softmax, fg
// argmax on raw logits (== prob argmax, first-occurrence ties), f64
// decode+clip+validity on lane 0. (math validated rounds 4-6; only the
// store layout changed to interleaved)
// =====================================================================
extern "C" __global__ __launch_bounds__(256)
void k_prep(const float* __restrict__ logits,
            const float* __restrict__ deltas,
            const float* __restrict__ props,
            double* __restrict__ w_act,
            float4* __restrict__ w_bh4,
            __half2* __restrict__ w_bl2,
            unsigned short* __restrict__ w_lab)
{
    const int wid  = blockIdx.x * 4 + (threadIdx.x >> 6);
    const int lane = threadIdx.x & 63;
    if (wid >= TOTALQ) return;

    const float* lg = logits + (long)wid * CNUM;
    const bool has1 = lane < (CNUM - 64);
    const float l0 = lg[lane];
    const float l1 = has1 ? lg[64 + lane] : 0.0f;

    float m = has1 ? fmaxf(l0, l1) : l0;
    #pragma unroll
    for (int s = 32; s; s >>= 1) m = fmaxf(m, __shfl_xor(m, s));

    const double e0 = exp((double)l0 - (double)m);
    const double e1 = has1 ? exp((double)l1 - (double)m) : 0.0;
    double sum = e0 + e1;
    #pragma unroll
    for (int s = 32; s; s >>= 1) sum += __shfl_xor(sum, s);

    float bv; int bc;
    if (lane >= 1) { bv = l0; bc = lane; } else { bv = -INFINITY; bc = 0x7fffffff; }
    if (has1 && l1 > bv) { bv = l1; bc = 64 + lane; }
    #pragma unroll
    for (int s = 32; s; s >>= 1) {
        const float ov = __shfl_xor(bv, s);
        const int   oc = __shfl_xor(bc, s);
        if (ov > bv || (ov == bv && oc < bc)) { bv = ov; bc = oc; }
    }

    if (lane == 0) {
        const int label = bc;
        const double score = exp((double)bv - (double)m) / sum;

        const float* pr = props + (long)wid * 4;
        const double x1p = (double)pr[0], y1p = (double)pr[1];
        const double x2p = (double)pr[2], y2p = (double)pr[3];
        const double w  = x2p - x1p, h = y2p - y1p;
        const double cx = x1p + 0.5 * w, cy = y1p + 0.5 * h;

        const float* dl = deltas + (long)wid * (CNUM * 4) + label * 4;
        const double dx = (double)dl[0] / 10.0;
        const double dy = (double)dl[1] / 10.0;
        const double dw = fmin((double)dl[2] / 5.0, CLAMP64);
        const double dh = fmin((double)dl[3] / 5.0, CLAMP64);

        const double pcx = dx * w + cx;
        const double pcy = dy * h + cy;
        const double pw  = exp(dw) * w;
        const double ph  = exp(dh) * h;

        double x1 = pcx - 0.5 * pw, y1 = pcy - 0.5 * ph;
        double x2 = pcx + 0.5 * pw, y2 = pcy + 0.5 * ph;
        x1 = fmin(fmax(x1, 0.0), 800.0);
        y1 = fmin(fmax(y1, 0.0), 800.0);
        x2 = fmin(fmax(x2, 0.0), 800.0);
        y2 = fmin(fmax(y2, 0.0), 800.0);

        const bool valid = ((x2 - x1) >= 0.01) && ((y2 - y1) >= 0.01) && (score > 0.05);

        w_act[wid] = valid ? score : NEGV;
        w_lab[wid] = (unsigned short)label;

        const float h0 = (float)x1, h1 = (float)y1, h2 = (float)x2, h3 = (float)y2;
        w_bh4[wid] = make_float4(h0, h1, h2, h3);
        __half2 p01, p23;
        p01.x = __float2half((float)(x1 - (double)h0));
        p01.y = __float2half((float)(y1 - (double)h1));
        p23.x = __float2half((float)(x2 - (double)h2));
        p23.y = __float2half((float)(y2 - (double)h3));
        w_bl2[2 * wid]     = p01;
        w_bl2[2 * wid + 1] = p23;
    }
}

// =====================================================================
// Kernel B: one wave per (image,label). Two-pass gather (label scan,
// then ONE batched scatter-load + ballot compaction), then the
// validated rank / IoU bit-row / serial-resolve NMS. Suppressed
// entries write NEGV back to w_act.
// =====================================================================
#define NCAP 256

extern "C" __global__ __launch_bounds__(64)
void k_nms4(double* w_act,
            const float4* __restrict__ w_bh4,
            const __half2* __restrict__ w_bl2,
            const unsigned short* __restrict__ w_lab)
{
    __shared__ int s_n, s_m;
    __shared__ int sj_raw[NCAP];
    __shared__ unsigned long long skey[NCAP];
    __shared__ int sj[NCAP];
    __shared__ double sx1[NCAP], sy1[NCAP], sx2[NCAP], sy2[NCAP];
    __shared__ unsigned short perm[NCAP];
    __shared__ unsigned long long rows[NCAP][4];

    const int img   = blockIdx.x / (CNUM - 1);
    const int label = 1 + (blockIdx.x % (CNUM - 1));
    const int lane  = threadIdx.x;
    const long base = (long)img * PNUM;

    if (lane == 0) { s_n = 0; s_m = 0; }
    __syncthreads();

    // ---- pass 1: label-only scan (u16x8 vector loads, no dependent scatter)
    for (int r = 0; r < (PNUM + 511) / 512; ++r) {
        const int j0 = r * 512 + lane * 8;
        if (j0 < PNUM) {   // j0 <= 3992 here, so all 8 elements are in range
            const u16x8 lv = *reinterpret_cast<const u16x8*>(&w_lab[base + j0]);
            #pragma unroll
            for (int t = 0; t < 8; ++t) {
                if ((int)lv[t] == label) {
                    const int s = atomicAdd(&s_n, 1);
                    if (s < NCAP) sj_raw[s] = j0 + t;
                }
            }
        }
    }
    __syncthreads();
    const int n = min(s_n, NCAP);
    if (n == 0) return;

    // ---- pass 2: batched loads (one candidate per lane, single wait),
    //      ballot compaction of valid (act > 0) candidates
    for (int r = 0; r * 64 < n; ++r) {
        const int s = r * 64 + lane;
        double a = -1.0; int j = 0; float4 hi = make_float4(0,0,0,0); uint2 lo = make_uint2(0,0);
        if (s < n) {
            j  = sj_raw[s];
            a  = w_act[base + j];
            hi = w_bh4[base + j];
            lo = ((const uint2*)w_bl2)[base + j];
        }
        const bool valid = (s < n) && (a > 0.0);
        const unsigned long long bm = __ballot(valid);
        int rbase;
        if (lane == 0) rbase = atomicAdd(&s_m, (int)__popcll(bm));
        rbase = __shfl(rbase, 0);
        if (valid) {
            const int pos = rbase + (int)__popcll(bm & ((1ull << lane) - 1ull));
            skey[pos] = (unsigned long long)__double_as_longlong(a);
            sj[pos]   = j;
            sx1[pos] = (double)hi.x + (double)h2f_bits(lo.x & 0xFFFFu);
            sy1[pos] = (double)hi.y + (double)h2f_bits(lo.x >> 16);
            sx2[pos] = (double)hi.z + (double)h2f_bits(lo.y & 0xFFFFu);
            sy2[pos] = (double)hi.w + (double)h2f_bits(lo.y >> 16);
        }
    }
    __syncthreads();
    const int m = s_m;
    if (m <= 1) return;

    // ---- rank by (key desc, j asc); ranks unique since j distinct ----
    for (int s = lane; s < m; s += 64) {
        const unsigned long long ks = skey[s];
        const int js = sj[s];
        int rank = 0;
        for (int q = 0; q < m; ++q) {
            const unsigned long long kq = skey[q];
            rank += (int)((kq > ks) || (kq == ks && sj[q] < js));
        }
        perm[rank] = (unsigned short)s;
    }
    __syncthreads();

    // ---- IoU bit-rows per sorted position (wave-parallel, f64) ----
    for (int p = lane; p < m; p += 64) {
        const int sp = perm[p];
        const double px1 = sx1[sp], py1 = sy1[sp], px2 = sx2[sp], py2 = sy2[sp];
        const double a1 = (px2 - px1) * (py2 - py1);
        #pragma unroll
        for (int w = 0; w < 4; ++w) {
            unsigned long long rw = 0;
            if (w * 64 < m) {
                const int qhi = min(m, w * 64 + 64);
                for (int q = w * 64; q < qhi; ++q) {
                    if (q == p) continue;
                    const int sq = perm[q];
                    const double qx1 = sx1[sq], qy1 = sy1[sq];
                    const double qx2 = sx2[sq], qy2 = sy2[sq];
                    const double ix = fmin(px2, qx2) - fmax(px1, qx1);
                    const double iy = fmin(py2, qy2) - fmax(py1, qy1);
                    const double inter = fmax(ix, 0.0) * fmax(iy, 0.0);
                    const double a2  = (qx2 - qx1) * (qy2 - qy1);
                    const double uni = fmax(a1 + a2 - inter, 1e-9);
                    if (inter / uni > 0.5) rw |= (1ull << (q & 63));
                }
            }
            rows[p][w] = rw;
        }
    }
    __syncthreads();

    // ---- serial greedy resolve (all lanes redundant; LDS broadcast) ----
    unsigned long long s0 = 0, s1 = 0, s2 = 0, s3 = 0;
    for (int i = 0; i < m; ++i) {
        const int w = i >> 6, b = i & 63;
        const unsigned long long sw = (w == 0) ? s0 : (w == 1) ? s1 : (w == 2) ? s2 : s3;
        if (!((sw >> b) & 1ull)) {
            s0 |= rows[i][0];
            s1 |= rows[i][1];
            s2 |= rows[i][2];
            s3 |= rows[i][3];
        }
    }

    // ---- write back suppressed ----
    for (int p = lane; p < m; p += 64) {
        const int w = p >> 6, b = p & 63;
        const unsigned long long sw = (w == 0) ? s0 : (w == 1) ? s1 : (w == 2) ? s2 : s3;
        if ((sw >> b) & 1ull)
            w_act[base + sj[perm[p]]] = NEGV;
    }
}

// =====================================================================
// Kernel C: one block per image. Histogram-select the rank-100 score
// threshold (parallel suffix scans, equivalent to validated serial
// walk), compact, exact rank-scatter by (key desc, idx asc).
// =====================================================================
#define NBINS 2304
#define NCH   128          // 72 real 32-bin chunks, padded to 128

extern "C" __global__ __launch_bounds__(1024)
void k_topk(const double* __restrict__ w_act,
            const float4* __restrict__ w_bh4,
            const unsigned short* __restrict__ w_lab,
            float* __restrict__ out)
{
    __shared__ int hist[NBINS];
    __shared__ int csum[NCH];
    __shared__ int ssuf[NCH];
    __shared__ int sT, sCh, scnt;
    __shared__ unsigned long long cKey[1024];
    __shared__ int cIdx[1024];
    __shared__ unsigned long long rKey[DETK];
    __shared__ int rIdx[DETK];

    const int n = blockIdx.x;
    const int tid = threadIdx.x;
    const long base = (long)n * PNUM;
    const unsigned long long KBASE = 0x3FA999999999999Aull >> 43;

    for (int i = tid; i < NBINS; i += 1024) hist[i] = 0;
    if (tid < DETK) rIdx[tid] = -1;
    if (tid == 0) { sT = 0; sCh = -1; scnt = 0; }
    __syncthreads();

    // histogram of survivor scores on top-21 bits (monotone for positive f64)
    for (int j = tid; j < PNUM; j += 1024) {
        const double a = w_act[base + j];
        if (a > 0.0) {
            const unsigned long long k = (unsigned long long)__double_as_longlong(a);
            int b = (int)((k >> 43) - KBASE);
            b = min(max(b, 0), NBINS - 1);
            atomicAdd(&hist[b], 1);
        }
    }
    __syncthreads();

    // per-chunk sums (32 bins/chunk), padded
    if (tid < NCH) {
        int s = 0;
        if (tid < NBINS / 32) {
            #pragma unroll
            for (int b = 0; b < 32; ++b) s += hist[tid * 32 + b];
        }
        csum[tid] = s;
        ssuf[tid] = s;
    }
    __syncthreads();

    // Hillis-Steele suffix sum over chunks
    for (int d = 1; d < NCH; d <<= 1) {
        int v = 0;
        if (tid < NCH) v = ssuf[tid] + ((tid + d < NCH) ? ssuf[tid + d] : 0);
        __syncthreads();
        if (tid < NCH) ssuf[tid] = v;
        __syncthreads();
    }

    // highest chunk whose suffix >= DETK
    if (tid < NCH && ssuf[tid] >= DETK && (tid == NCH - 1 || ssuf[tid + 1] < DETK))
        sCh = tid;
    __syncthreads();

    // within-chunk: highest bin with suffix_count >= DETK (one wave, shfl)
    if (tid < 64) {
        const int ch = sCh;
        if (ch >= 0) {
            int W = (tid < 32) ? hist[ch * 32 + tid] : 0;
            #pragma unroll
            for (int off = 1; off < 64; off <<= 1) {
                const int o = __shfl_down(W, off);
                W += (tid + off < 64) ? o : 0;
            }
            const int Shi = (ch < NCH - 1) ? ssuf[ch + 1] : 0;
            const unsigned long long Mk = __ballot((tid < 32) && (W + Shi >= DETK));
            if (tid == 0) sT = (Mk != 0ull) ? (ch * 32 + (63 - __clzll(Mk))) : 0;
        }
    }
    __syncthreads();
    const int T = sT;

    // compact candidates in bins >= T
    for (int j = tid; j < PNUM; j += 1024) {
        const double a = w_act[base + j];
        if (a > 0.0) {
            const unsigned long long k = (unsigned long long)__double_as_longlong(a);
            int b = (int)((k >> 43) - KBASE);
            b = min(max(b, 0), NBINS - 1);
            if (b >= T) {
                const int p = atomicAdd(&scnt, 1);
                if (p < 1024) { cKey[p] = k; cIdx[p] = j; }
            }
        }
    }
    __syncthreads();
    const int cnt = min(scnt, 1024);

    // exact rank-scatter by (key desc, idx asc); ranks unique
    for (int s = tid; s < cnt; s += 1024) {
        const unsigned long long ks = cKey[s];
        const int is = cIdx[s];
        int rank = 0;
        for (int q = 0; q < cnt; ++q) {
            const unsigned long long kq = cKey[q];
            rank += (int)((kq > ks) || (kq == ks && cIdx[q] < is));
        }
        if (rank < DETK) { rKey[rank] = ks; rIdx[rank] = is; }
    }
    __syncthreads();

    // emit top-100
    if (tid < DETK) {
        const int o = n * DETK + tid;
        const int idx = rIdx[tid];
        const bool kp = (idx >= 0);
        float lab = 0.f, sc = 0.f, b0 = 0.f, b1 = 0.f, b2 = 0.f, b3 = 0.f;
        if (kp) {
            lab = (float)w_lab[base + idx];
            sc  = (float)__longlong_as_double((long long)rKey[tid]);
            const float4 bh = w_bh4[base + idx];   // hi part == (float)x64 exactly
            b0 = bh.x; b1 = bh.y; b2 = bh.z; b3 = bh.w;
        }
        out[o]               = lab;
        out[NIMG * DETK + o] = sc;
        out[2 * NIMG * DETK + o * 4 + 0] = b0;
        out[2 * NIMG * DETK + o * 4 + 1] = b1;
        out[2 * NIMG * DETK + o * 4 + 2] = b2;
        out[2 * NIMG * DETK + o * 4 + 3] = b3;
    }
}

// =====================================================================
// Fallback (proven round-3 kernel) in case ws_size < WS_NEED.
// =====================================================================
extern "C" __global__ __launch_bounds__(1024)
void k_fused(const float* __restrict__ logits,
             const float* __restrict__ deltas,
             const float* __restrict__ props,
             float* __restrict__ out)
{
    __shared__ float   bh0[PNUM], bh1[PNUM], bh2[PNUM], bh3[PNUM];
    __shared__ __half  bl0[PNUM], bl1[PNUM], bl2[PNUM], bl3[PNUM];
    __shared__ double  act[PNUM];
    __shared__ unsigned short slab[PNUM];
    __shared__ double  redV[16];
    __shared__ int     redI[16];
    __shared__ double  pbox[4];
    __shared__ int     pidx, pkeep, plab;
    __shared__ int     kidx[DETK], kkeep[DETK];
    __shared__ double  kscore[DETK];
    __shared__ double  kbox[DETK][4];

    const int n   = blockIdx.x;
    const int tid = threadIdx.x;

    for (int j = tid; j < PNUM; j += 1024) {
        const long q = (long)n * PNUM + j;
        const float* lg = logits + q * CNUM;
        float ml = lg[0];
        float bv = lg[1];
        int   lab = 1;
        for (int c = 1; c < CNUM; ++c) {
            const float v = lg[c];
            ml = fmaxf(ml, v);
            if (c >= 2 && v > bv) { bv = v; lab = c; }
        }
        const double m = (double)ml;
        double sum = 0.0;
        for (int c = 0; c < CNUM; ++c) sum += exp((double)lg[c] - m);
        const double score = exp((double)bv - m) / sum;

        const float* pr = props + q * 4;
        const double x1p = (double)pr[0], y1p = (double)pr[1];
        const double x2p = (double)pr[2], y2p = (double)pr[3];
        const double w  = x2p - x1p, h = y2p - y1p;
        const double cx = x1p + 0.5 * w, cy = y1p + 0.5 * h;
        const float* dl = deltas + q * (CNUM * 4) + lab * 4;
        const double dx = (double)dl[0] / 10.0;
        const double dy = (double)dl[1] / 10.0;
        const double dw = fmin((double)dl[2] / 5.0, CLAMP64);
        const double dh = fmin((double)dl[3] / 5.0, CLAMP64);
        const double pcx = dx * w + cx;
        const double pcy = dy * h + cy;
        const double pw  = exp(dw) * w;
        const double ph  = exp(dh) * h;
        double x1 = pcx - 0.5 * pw, y1 = pcy - 0.5 * ph;
        double x2 = pcx + 0.5 * pw, y2 = pcy + 0.5 * ph;
        x1 = fmin(fmax(x1, 0.0), 800.0);
        y1 = fmin(fmax(y1, 0.0), 800.0);
        x2 = fmin(fmax(x2, 0.0), 800.0);
        y2 = fmin(fmax(y2, 0.0), 800.0);
        const bool valid = ((x2 - x1) >= 0.01) && ((y2 - y1) >= 0.01) && (score > 0.05);
        act[j]  = valid ? score : NEGV;
        slab[j] = (unsigned short)lab;
        const float h0 = (float)x1, h1 = (float)y1, h2 = (float)x2, h3 = (float)y2;
        bh0[j] = h0; bh1[j] = h1; bh2[j] = h2; bh3[j] = h3;
        bl0[j] = __float2half((float)(x1 - (double)h0));
        bl1[j] = __float2half((float)(y1 - (double)h1));
        bl2[j] = __float2half((float)(x2 - (double)h2));
        bl3[j] = __float2half((float)(y2 - (double)h3));
    }
    __syncthreads();

    for (int k = 0; k < DETK; ++k) {
        double bv = -INFINITY;
        int    bi = 0x7fffffff;
        #pragma unroll
        for (int t = 0; t < 4; ++t) {
            const int j = tid + t * 1024;
            if (j < PNUM) {
                const double v = act[j];
                if (v > bv) { bv = v; bi = j; }
            }
        }
        #pragma unroll
        for (int s = 32; s; s >>= 1) {
            const double ov = __shfl_xor(bv, s);
            const int    oi = __shfl_xor(bi, s);
            if (ov > bv || (ov == bv && oi < bi)) { bv = ov; bi = oi; }
        }
        if ((tid & 63) == 0) { redV[tid >> 6] = bv; redI[tid >> 6] = bi; }
        __syncthreads();
        if (tid < 64) {
            bv = (tid < 16) ? redV[tid] : -INFINITY;
            bi = (tid < 16) ? redI[tid] : 0x7fffffff;
            #pragma unroll
            for (int s = 8; s; s >>= 1) {
                const double ov = __shfl_xor(bv, s);
                const int    oi = __shfl_xor(bi, s);
                if (ov > bv || (ov == bv && oi < bi)) { bv = ov; bi = oi; }
            }
            if (tid == 0) {
                const int kp = (bv > NEGH) ? 1 : 0;
                pidx = bi; pkeep = kp; plab = (int)slab[bi];
                kidx[k] = bi; kkeep[k] = kp; kscore[k] = bv;
                const double b0 = (double)bh0[bi] + (double)__half2float(bl0[bi]);
                const double b1 = (double)bh1[bi] + (double)__half2float(bl1[bi]);
                const double b2 = (double)bh2[bi] + (double)__half2float(bl2[bi]);
                const double b3 = (double)bh3[bi] + (double)__half2float(bl3[bi]);
                pbox[0] = b0; pbox[1] = b1; pbox[2] = b2; pbox[3] = b3;
                kbox[k][0] = b0; kbox[k][1] = b1; kbox[k][2] = b2; kbox[k][3] = b3;
            }
        }
        __syncthreads();

        const int    pick = pidx;
        const int    kp   = pkeep;
        const int    pl   = plab;
        const double px1 = pbox[0], py1 = pbox[1], px2 = pbox[2], py2 = pbox[3];
        const double a1  = (px2 - px1) * (py2 - py1);
        #pragma unroll
        for (int t = 0; t < 4; ++t) {
            const int j = tid + t * 1024;
            if (j >= PNUM) break;
            if (j == pick) { act[j] = NEGV; continue; }
            if (!kp) continue;
            if ((int)slab[j] != pl) continue;
            if (act[j] <= NEGH) continue;
            const double qx1 = (double)bh0[j] + (double)__half2float(bl0[j]);
            const double qy1 = (double)bh1[j] + (double)__half2float(bl1[j]);
            const double qx2 = (double)bh2[j] + (double)__half2float(bl2[j]);
            const double qy2 = (double)bh3[j] + (double)__half2float(bl3[j]);
            const double ix = fmin(px2, qx2) - fmax(px1, qx1);
            const double iy = fmin(py2, qy2) - fmax(py1, qy1);
            const double inter = fmax(ix, 0.0) * fmax(iy, 0.0);
            const double a2  = (qx2 - qx1) * (qy2 - qy1);
            const double uni = fmax(a1 + a2 - inter, 1e-9);
            if (inter / uni > 0.5) act[j] = NEGV;
        }
        __syncthreads();
    }

    if (tid < DETK) {
        const int kp = kkeep[tid];
        const int o  = n * DETK + tid;
        out[o]               = kp ? (float)slab[kidx[tid]] : 0.0f;
        out[NIMG * DETK + o] = kp ? (float)kscore[tid] : 0.0f;
        #pragma unroll
        for (int i = 0; i < 4; ++i)
            out[2 * NIMG * DETK + o * 4 + i] = kp ? (float)kbox[tid][i] : 0.0f;
    }
}

extern "C" void kernel_launch(void* const* d_in, const int* in_sizes, int n_in,
                              void* d_out, int out_size, void* d_ws, size_t ws_size,
                              hipStream_t stream)
{
    const float* logits = (const float*)d_in[1];
    const float* deltas = (const float*)d_in[2];
    const float* props  = (const float*)d_in[3];
    float* out = (float*)d_out;

    if (ws_size >= (size_t)WS_NEED) {
        char* ws = (char*)d_ws;
        double*         w_act = (double*)(ws + WS_ACT);
        float4*         w_bh4 = (float4*)(ws + WS_BH4);
        __half2*        w_bl2 = (__half2*)(ws + WS_BL2);
        unsigned short* w_lab = (unsigned short*)(ws + WS_LAB);

        hipLaunchKernelGGL(k_prep, dim3(TOTALQ / 4), dim3(256), 0, stream,
                           logits, deltas, props, w_act, w_bh4, w_bl2, w_lab);
        hipLaunchKernelGGL(k_nms4, dim3(NIMG * (CNUM - 1)), dim3(64), 0, stream,
                           w_act, w_bh4, w_bl2, w_lab);
        hipLaunchKernelGGL(k_topk, dim3(NIMG), dim3(1024), 0, stream,
                           w_act, w_bh4, w_lab, out);
    } else {
        hipLaunchKernelGGL(k_fused, dim3(NIMG), dim3(1024), 0, stream,
                           logits, deltas, props, out);
    }
}